// Round 9
// baseline (372.751 us; speedup 1.0000x reference)
//
#include <hip/hip_runtime.h>
#include <hip/hip_bf16.h>

#define NN 20000
#define NP1 20001
#define DIM 256
#define NE 320000

#define NBKT 79        // buckets of 256 dst rows (last bucket = 32 rows)
#define BROWS 256
#define ACH 4096       // edges per phase-A chunk
#define ABLK 79        // ceil(NE/ACH)
#define STAGE_CAP 6144
#define APAD 260       // aggA row stride (shorts): 64x260 -> conflict-free frag reads

typedef __attribute__((ext_vector_type(8))) short short8v;   // 8 bf16 = 4 VGPRs
typedef __attribute__((ext_vector_type(4))) float float4v;
typedef __attribute__((ext_vector_type(2))) float float2v;
typedef __attribute__((ext_vector_type(8))) unsigned short ushort8v;

typedef __attribute__((address_space(3))) void lds_vp;
typedef const __attribute__((address_space(1))) void gbl_vp;

__device__ __forceinline__ unsigned short f2bf(float f) {
    unsigned int u = __float_as_uint(f);
    u += 0x7fffu + ((u >> 16) & 1u);          // round-to-nearest-even
    return (unsigned short)(u >> 16);
}
__device__ __forceinline__ unsigned char f2fp8(float f) {
    return (unsigned char)(__builtin_amdgcn_cvt_pk_fp8_f32(f, f, 0, 0) & 0xff);
}

__device__ __forceinline__ int slot_to_rel(int s) { return (s == 3) ? 4 : s; }

// ---------------------------------------------------------------------------
// Fused setup: bucket partial hist (atomic-free, private slices) |
// x -> {bf16, fp8} | weight prep
// ---------------------------------------------------------------------------
#define HIST_BLOCKS (4 * ABLK)             // 316
#define CONV_BLOCKS 7500                   // 3*NN*DIM / (256*8)
#define PREP_BLOCKS 768                    // 3 * 256

__global__ __launch_bounds__(256) void setup_kernel(const float* __restrict__ x,
                                                    const int* __restrict__ edges,
                                                    const float* __restrict__ Wr1,
                                                    const float* __restrict__ br1,
                                                    const float* __restrict__ Wo1,
                                                    const float* __restrict__ Wr2,
                                                    const float* __restrict__ br2,
                                                    const float* __restrict__ Wo2,
                                                    int* __restrict__ part,       // [4][ABLK][NBKT]
                                                    unsigned short* __restrict__ xb,
                                                    unsigned char* __restrict__ xq,
                                                    unsigned short* __restrict__ BT,
                                                    float* __restrict__ biascat) {
    int b = blockIdx.x;
    if (b < HIST_BLOCKS) {
        int s = b / ABLK, a = b - s * ABLK;
        int k = slot_to_rel(s);
        __shared__ int cnt[NBKT];
        for (int t = threadIdx.x; t < NBKT; t += 256) cnt[t] = 0;
        __syncthreads();
        int e0 = a * ACH;
        #pragma unroll
        for (int j = 0; j < 16; ++j) {
            int e = e0 + j * 256 + threadIdx.x;
            if (e < NE) atomicAdd(&cnt[edges[k * 2 * NE + NE + e] >> 8], 1);
        }
        __syncthreads();
        for (int t = threadIdx.x; t < NBKT; t += 256)
            part[(s * ABLK + a) * NBKT + t] = cnt[t];
    } else if (b < HIST_BLOCKS + CONV_BLOCKS) {
        size_t i = ((size_t)(b - HIST_BLOCKS) * 256 + threadIdx.x) * 8;
        float4 v0 = *(const float4*)(x + i);
        float4 v1 = *(const float4*)(x + i + 4);
        if (i < 2 * (size_t)NN * DIM) {    // bf16 roots only needed for types 0,1
            ushort8v o;
            o[0] = f2bf(v0.x); o[1] = f2bf(v0.y); o[2] = f2bf(v0.z); o[3] = f2bf(v0.w);
            o[4] = f2bf(v1.x); o[5] = f2bf(v1.y); o[6] = f2bf(v1.z); o[7] = f2bf(v1.w);
            *(ushort8v*)(xb + i) = o;
        }
        unsigned int w0 = __builtin_amdgcn_cvt_pk_fp8_f32(v0.x, v0.y, 0, 0);
        w0 = __builtin_amdgcn_cvt_pk_fp8_f32(v0.z, v0.w, w0, 1);
        unsigned int w1 = __builtin_amdgcn_cvt_pk_fp8_f32(v1.x, v1.y, 0, 0);
        w1 = __builtin_amdgcn_cvt_pk_fp8_f32(v1.z, v1.w, w1, 1);
        *(uint2*)(xq + i) = make_uint2(w0, w1);
    } else {
        int pb = b - HIST_BLOCKS - CONV_BLOCKS;
        int g = pb >> 8, n = pb & 255;
        const float* Wr = (g == 2) ? Wr2 : Wr1;
        const float* Wo = (g == 2) ? Wo2 : Wo1;
        const float* br = (g == 2) ? br2 : br1;
        int ka = (g == 1) ? 1 : 0;
        int kb = (g == 1) ? 4 : 2;
        for (int c = 0; c < 3; ++c) {
            int k = c * 256 + threadIdx.x;
            float v;
            if (k < 256)      v = Wr[(size_t)ka * 65536 + k * 256 + n];
            else if (k < 512) v = Wr[(size_t)kb * 65536 + (k - 256) * 256 + n];
            else              v = Wo[(size_t)ka * 65536 + (k - 512) * 256 + n] +
                                  Wo[(size_t)kb * 65536 + (k - 512) * 256 + n];
            BT[(size_t)g * 768 * 256 + (size_t)n * 768 + k] = f2bf(v);
        }
        if (n == 0) biascat[g * DIM + threadIdx.x] =
            br[ka * DIM + threadIdx.x] + br[kb * DIM + threadIdx.x];
    }
}

// ---------------------------------------------------------------------------
// Phase A: bin edges bucket-major (atomic-free offsets from partial counts)
// ---------------------------------------------------------------------------
__global__ __launch_bounds__(256) void binA_scatter_kernel(const int* __restrict__ edges,
                                                           const int* __restrict__ part,
                                                           uint2* __restrict__ pairs) {
    int s = blockIdx.y, a0 = blockIdx.x;
    int k = slot_to_rel(s);
    const int* P = part + (size_t)s * ABLK * NBKT;
    __shared__ int tot[NBKT], pre[NBKT], bstart[NBKT];
    __shared__ int scn[NBKT], cur[NBKT], gb[NBKT];
    __shared__ uint2 st[ACH];
    if (threadIdx.x < NBKT) {
        int t = threadIdx.x, s_tot = 0, s_pre = 0;
        for (int a = 0; a < ABLK; ++a) {
            int v = P[a * NBKT + t];
            s_tot += v; if (a < a0) s_pre += v;
        }
        tot[t] = s_tot; pre[t] = s_pre;
    }
    __syncthreads();
    if (threadIdx.x == 0) {
        int run = 0;
        for (int b = 0; b < NBKT; ++b) { bstart[b] = run; run += tot[b]; }
        run = 0;
        for (int b = 0; b < NBKT; ++b) { scn[b] = run; run += P[a0 * NBKT + b]; }
    }
    __syncthreads();
    if (threadIdx.x < NBKT) {
        int t = threadIdx.x;
        cur[t] = scn[t];
        gb[t] = bstart[t] + pre[t] - scn[t];
    }
    __syncthreads();
    int e0 = a0 * ACH;
    #pragma unroll
    for (int j = 0; j < 16; ++j) {
        int e = e0 + j * 256 + threadIdx.x;
        if (e < NE) {
            unsigned int src = edges[k * 2 * NE + e];
            unsigned int dst = edges[k * 2 * NE + NE + e];
            int slot = atomicAdd(&cur[dst >> 8], 1);
            st[slot] = make_uint2(src, dst);
        }
    }
    __syncthreads();
    int nthis = NE - e0; if (nthis > ACH) nthis = ACH;
    for (int i = threadIdx.x; i < nthis; i += 256) {
        uint2 p = st[i];
        pairs[(size_t)s * NE + gb[p.y >> 8] + i] = p;
    }
}

// ---------------------------------------------------------------------------
// Phase B: per (bucket, slot) — row counts + scan in LDS -> row_start,
// LDS-atomic scatter to staging, coalesced esorted write.
// ---------------------------------------------------------------------------
__global__ __launch_bounds__(256) void binB_kernel(const uint2* __restrict__ pairs,
                                                   const int* __restrict__ part,
                                                   int* __restrict__ row_start,
                                                   int* __restrict__ esorted) {
    int s = blockIdx.y, b = blockIdx.x;
    const int* P = part + (size_t)s * ABLK * NBKT;
    __shared__ int tot[NBKT], bstartS[NBKT + 1];
    if (threadIdx.x < NBKT) {
        int t = threadIdx.x, s_tot = 0;
        for (int a = 0; a < ABLK; ++a) s_tot += P[a * NBKT + t];
        tot[t] = s_tot;
    }
    __syncthreads();
    if (threadIdx.x == 0) {
        int run = 0;
        for (int j = 0; j < NBKT; ++j) { bstartS[j] = run; run += tot[j]; }
        bstartS[NBKT] = run;
    }
    __syncthreads();
    int base = bstartS[b], end = bstartS[b + 1];
    int n = end - base;
    int row0 = b * BROWS;
    int nrows = NN - row0; if (nrows > BROWS) nrows = BROWS;

    __shared__ int rcnt[BROWS];
    __shared__ int rcur[BROWS];
    __shared__ int stg[STAGE_CAP];
    __shared__ int w4[4];
    rcnt[threadIdx.x] = 0;
    __syncthreads();
    for (int i = threadIdx.x; i < n; i += 256) {
        uint2 p = pairs[(size_t)s * NE + base + i];
        atomicAdd(&rcnt[p.y & 255], 1);
    }
    __syncthreads();
    int lane = threadIdx.x & 63, w = threadIdx.x >> 6;
    int v = rcnt[threadIdx.x];
    int x = v;
    #pragma unroll
    for (int off = 1; off < 64; off <<= 1) {
        int t = __shfl_up(x, off, 64);
        if (lane >= off) x += t;
    }
    if (lane == 63) w4[w] = x;
    __syncthreads();
    int woff = 0;
    for (int j = 0; j < w; ++j) woff += w4[j];
    int excl = x - v + woff;
    if (threadIdx.x < nrows) row_start[s * NP1 + row0 + threadIdx.x] = base + excl;
    if (b == NBKT - 1 && threadIdx.x == 0) row_start[s * NP1 + NN] = end;
    rcur[threadIdx.x] = excl;
    __syncthreads();

    if (n <= STAGE_CAP) {
        for (int i = threadIdx.x; i < n; i += 256) {
            uint2 p = pairs[(size_t)s * NE + base + i];
            int pos = atomicAdd(&rcur[p.y & 255], 1);
            stg[pos] = (int)p.x;
        }
        __syncthreads();
        for (int i = threadIdx.x; i < n; i += 256)
            esorted[(size_t)s * NE + base + i] = stg[i];
    } else {  // pathological fallback
        for (int i = threadIdx.x; i < n; i += 256) {
            uint2 p = pairs[(size_t)s * NE + base + i];
            int pos = atomicAdd(&rcur[p.y & 255], 1);
            esorted[(size_t)s * NE + base + pos] = (int)p.x;
        }
    }
}

// ---------------------------------------------------------------------------
// fp8 edge accumulate helper (16 values per lane from one uint4)
// ---------------------------------------------------------------------------
__device__ __forceinline__ void acc_row16(float2v* a2, uint4 raw) {
    float2v f;
    f = __builtin_amdgcn_cvt_pk_f32_fp8(raw.x, 0); a2[0] += f;
    f = __builtin_amdgcn_cvt_pk_f32_fp8(raw.x, 1); a2[1] += f;
    f = __builtin_amdgcn_cvt_pk_f32_fp8(raw.y, 0); a2[2] += f;
    f = __builtin_amdgcn_cvt_pk_f32_fp8(raw.y, 1); a2[3] += f;
    f = __builtin_amdgcn_cvt_pk_f32_fp8(raw.z, 0); a2[4] += f;
    f = __builtin_amdgcn_cvt_pk_f32_fp8(raw.z, 1); a2[5] += f;
    f = __builtin_amdgcn_cvt_pk_f32_fp8(raw.w, 0); a2[6] += f;
    f = __builtin_amdgcn_cvt_pk_f32_fp8(raw.w, 1); a2[7] += f;
}

// ---------------------------------------------------------------------------
// Fused gather-GEMM(+loss): block = 256 threads (4 waves), tile M=64 x N=256.
// Each block owns 64 dst rows exclusively:
//   seg 0/1: aggregate fp8 src rows (quad-per-row, 2-edge unroll) -> bf16 LDS
//            aggA (padded, conflict-free A-frag reads); K-loop stages B only.
//   seg 2:   root bf16 staged via global_load_lds into aggA's first 4 KB.
// mode 0: relu + write bf16 h + fp8 shadow.  mode 1: in-block softmax -> nll.
// ---------------------------------------------------------------------------
struct FusedArgs {
    const unsigned char* featA[2];  // fp8 features for slotA gather
    const unsigned char* featB[2];
    int slotA[2], slotB[2];
    const unsigned short* root[2];  // bf16 root features (A seg2)
    const unsigned short* BT[2];    // [256][768] bf16
    const float* bias[2];
    unsigned short* Cb[2];          // bf16 out (mode 0)
    unsigned char* Cq[2];           // fp8 shadow out (mode 0)
    const int* y;                   // (mode 1)
    float* nll;                     // (mode 1)
    int mode;
};

__global__ __launch_bounds__(256) void gemm_fused_kernel(FusedArgs fa,
                                                         const int* __restrict__ row_start,
                                                         const int* __restrict__ esorted) {
    __shared__ unsigned short aggA[64 * APAD];   // 33.3 KB (seg2 aliases first 4 KB)
    __shared__ unsigned short Btile[256 * 32];   // 16 KB
    __shared__ float redm[64][4];
    __shared__ float reds[64][4];
    __shared__ float ylog[64];
    __shared__ int ylds[64];

    int z = blockIdx.y;
    int tid = threadIdx.x;
    int wave = tid >> 6, lane = tid & 63;
    int q = lane >> 4, r = lane & 15;
    int wc = wave;                     // wave's 64-col slice
    int row0 = blockIdx.x * 64;

    if (fa.mode && tid < 64) {
        int rowg = row0 + tid;
        ylds[tid] = (rowg < NN) ? fa.y[rowg] : -1;
    }

    const unsigned short* BT = fa.BT[z];
    int bn = tid >> 2, bk8 = (tid & 3) * 8;
    int rrow = row0 + (tid >> 2); if (rrow > NN - 1) rrow = NN - 1;
    size_t rootoff = (size_t)rrow * DIM + bk8;

    float4v acc[4][4] = {};

    #pragma unroll 1
    for (int seg = 0; seg < 3; ++seg) {
        if (seg < 2) {
            int slot = seg ? fa.slotB[z] : fa.slotA[z];
            const unsigned char* feat = seg ? fa.featB[z] : fa.featA[z];
            const int* rs = row_start + slot * NP1;
            const int* es = esorted + slot * NE;
            __syncthreads();           // protect aggA from previous readers
            #pragma unroll 1
            for (int rr = 0; rr < 4; ++rr) {
                int rl = wave * 16 + q * 4 + rr;   // local row 0..63
                int row = row0 + rl;
                float2v a2[8] = {};
                if (row < NN) {
                    int b = rs[row], e = rs[row + 1];
                    int i = b;
                    #pragma unroll 1
                    for (; i + 1 < e; i += 2) {
                        int s0 = es[i], s1 = es[i + 1];
                        uint4 r0 = *(const uint4*)(feat + (size_t)s0 * DIM + r * 16);
                        uint4 r1 = *(const uint4*)(feat + (size_t)s1 * DIM + r * 16);
                        acc_row16(a2, r0);
                        acc_row16(a2, r1);
                    }
                    if (i < e) {
                        uint4 r0 = *(const uint4*)(feat + (size_t)es[i] * DIM + r * 16);
                        acc_row16(a2, r0);
                    }
                }
                ushort8v o0, o1;
                #pragma unroll
                for (int j = 0; j < 4; ++j) {
                    o0[2 * j] = f2bf(a2[j].x);     o0[2 * j + 1] = f2bf(a2[j].y);
                    o1[2 * j] = f2bf(a2[4 + j].x); o1[2 * j + 1] = f2bf(a2[4 + j].y);
                }
                int ad = rl * APAD + r * 16;
                *(ushort8v*)&aggA[ad] = o0;
                *(ushort8v*)&aggA[ad + 8] = o1;
            }
            __syncthreads();
        }
        #pragma unroll 1
        for (int kt = 0; kt < 8; ++kt) {
            int kb = seg * 256 + kt * 32;
            #pragma unroll
            for (int c = 0; c < 4; ++c) {
                __builtin_amdgcn_global_load_lds(
                    (gbl_vp*)(BT + (size_t)(c * 64 + bn) * 768 + kb + bk8),
                    (lds_vp*)&Btile[c * 2048 + (tid & ~63) * 8], 16, 0, 0);
            }
            if (seg == 2) {
                __builtin_amdgcn_global_load_lds(
                    (gbl_vp*)(fa.root[z] + rootoff + kt * 32),
                    (lds_vp*)&aggA[(tid & ~63) * 8], 16, 0, 0);
            }
            __syncthreads();
            short8v a[4], b[4];
            #pragma unroll
            for (int i = 0; i < 4; ++i) {
                a[i] = (seg < 2)
                    ? *(const short8v*)&aggA[(i * 16 + r) * APAD + kt * 32 + q * 8]
                    : *(const short8v*)&aggA[(i * 16 + r) * 32 + q * 8];
            }
            #pragma unroll
            for (int j = 0; j < 4; ++j)
                b[j] = *(const short8v*)&Btile[(wc * 64 + j * 16 + r) * 32 + q * 8];
            #pragma unroll
            for (int i = 0; i < 4; ++i)
                #pragma unroll
                for (int j = 0; j < 4; ++j)
                    acc[i][j] = __builtin_amdgcn_mfma_f32_16x16x32_bf16(a[i], b[j], acc[i][j], 0, 0, 0);
            __syncthreads();
        }
    }

    // Epilogue. C/D layout: col = r, row = q*4 + e (within each 16x16 tile).
    float bj[4];
    #pragma unroll
    for (int j = 0; j < 4; ++j) bj[j] = fa.bias[z][wc * 64 + j * 16 + r];

    if (fa.mode == 0) {
        unsigned short* Cb = fa.Cb[z];
        unsigned char* Cq = fa.Cq[z];
        #pragma unroll
        for (int i = 0; i < 4; ++i) {
            int rowb = row0 + i * 16 + q * 4;
            #pragma unroll
            for (int e = 0; e < 4; ++e) {
                int rowc = rowb + e;
                if (rowc < NN) {
                    #pragma unroll
                    for (int j = 0; j < 4; ++j) {
                        int col = wc * 64 + j * 16 + r;
                        float v = fmaxf(acc[i][j][e] + bj[j], 0.f);
                        Cb[(size_t)rowc * DIM + col] = f2bf(v);
                        Cq[(size_t)rowc * DIM + col] = f2fp8(v);
                    }
                }
            }
        }
    } else {
        #pragma unroll
        for (int i = 0; i < 4; ++i) {
            #pragma unroll
            for (int e = 0; e < 4; ++e) {
                int row_local = i * 16 + q * 4 + e;
                int ycls = ylds[row_local];
                float v[4];
                float m = -3.4e38f;
                #pragma unroll
                for (int j = 0; j < 4; ++j) {
                    v[j] = acc[i][j][e] + bj[j];
                    m = fmaxf(m, v[j]);
                    int col = wc * 64 + j * 16 + r;
                    if (col == ycls) ylog[row_local] = v[j];
                }
                #pragma unroll
                for (int off = 1; off < 16; off <<= 1) m = fmaxf(m, __shfl_xor(m, off, 64));
                float s = __expf(v[0] - m) + __expf(v[1] - m) +
                          __expf(v[2] - m) + __expf(v[3] - m);
                #pragma unroll
                for (int off = 1; off < 16; off <<= 1) s += __shfl_xor(s, off, 64);
                if (r == 0) { redm[row_local][wc] = m; reds[row_local][wc] = s; }
            }
        }
        __syncthreads();
        if (tid < 64) {
            int rowg = row0 + tid;
            if (rowg < NN) {
                float m0 = redm[tid][0], m1 = redm[tid][1], m2 = redm[tid][2], m3 = redm[tid][3];
                float mm = fmaxf(fmaxf(m0, m1), fmaxf(m2, m3));
                float ss = reds[tid][0] * __expf(m0 - mm) + reds[tid][1] * __expf(m1 - mm) +
                           reds[tid][2] * __expf(m2 - mm) + reds[tid][3] * __expf(m3 - mm);
                fa.nll[rowg] = mm + __logf(ss) - ylog[tid];
            }
        }
    }
}

__global__ __launch_bounds__(256) void reduce_mean_kernel(const float* __restrict__ nll,
                                                          float* __restrict__ out) {
    float s = 0.f;
    for (int i = threadIdx.x; i < NN; i += 256) s += nll[i];
    #pragma unroll
    for (int off = 32; off; off >>= 1) s += __shfl_xor(s, off, 64);
    __shared__ float ws_[4];
    int w = threadIdx.x >> 6, lane = threadIdx.x & 63;
    if (lane == 0) ws_[w] = s;
    __syncthreads();
    if (threadIdx.x == 0) out[0] = (ws_[0] + ws_[1] + ws_[2] + ws_[3]) / (float)NN;
}

// ---------------------------------------------------------------------------
extern "C" void kernel_launch(void* const* d_in, const int* in_sizes, int n_in,
                              void* d_out, int out_size, void* d_ws, size_t ws_size,
                              hipStream_t stream) {
    const float* x    = (const float*)d_in[0];
    const int*   edges= (const int*)d_in[1];
    const int*   y    = (const int*)d_in[2];
    const float* Wr1  = (const float*)d_in[3];
    const float* br1  = (const float*)d_in[4];
    const float* Wo1  = (const float*)d_in[5];
    const float* Wr2  = (const float*)d_in[6];
    const float* br2  = (const float*)d_in[7];
    const float* Wo2  = (const float*)d_in[8];
    float* out = (float*)d_out;

    char* ws = (char*)d_ws;
    size_t off = 0;
    auto alloc = [&](size_t bytes) {
        char* p = ws + off;
        off += (bytes + 511) & ~size_t(511);
        return p;
    };
    int*   part          = (int*)alloc(4 * (size_t)ABLK * NBKT * sizeof(int));
    uint2* pairs         = (uint2*)alloc(4 * (size_t)NE * sizeof(uint2));
    int*   rowstart      = (int*)alloc(4 * NP1 * sizeof(int));
    int*   esorted       = (int*)alloc(4 * (size_t)NE * sizeof(int));
    unsigned short* BT      = (unsigned short*)alloc(3 * 768 * (size_t)DIM * 2);
    float*          biascat = (float*)         alloc(3 * DIM * sizeof(float));
    unsigned short* xb      = (unsigned short*)alloc(2 * (size_t)NN * DIM * 2);
    unsigned char*  xq      = (unsigned char*) alloc(3 * (size_t)NN * DIM);
    unsigned short* h0      = (unsigned short*)alloc((size_t)NN * DIM * 2);
    unsigned short* h1      = (unsigned short*)alloc((size_t)NN * DIM * 2);
    unsigned char*  h0q     = (unsigned char*) alloc((size_t)NN * DIM);
    unsigned char*  h1q     = (unsigned char*) alloc((size_t)NN * DIM);
    float*          nll     = (float*)         alloc(NN * sizeof(float));
    (void)in_sizes; (void)n_in; (void)out_size; (void)ws_size;

    const size_t ND = (size_t)NN * DIM;

    // 1. Fused setup (bucket partial hist | x->bf16/fp8 | weights)
    setup_kernel<<<dim3(HIST_BLOCKS + CONV_BLOCKS + PREP_BLOCKS), 256, 0, stream>>>(
        x, edges, Wr1, br1, Wo1, Wr2, br2, Wo2, part, xb, xq, BT, biascat);

    // 2. Bucket sort: bin (atomic-free offsets) -> per-bucket scatter
    binA_scatter_kernel<<<dim3(ABLK, 4), 256, 0, stream>>>(edges, part, pairs);
    binB_kernel<<<dim3(NBKT, 4), 256, 0, stream>>>(pairs, part, rowstart, esorted);

    // 3. Layer-1 fused gather-GEMM (both dst types via blockIdx.y)
    {
        FusedArgs fa;
        // z=0 (dst t0): slots 0 (src xq t0), 2 (src xq t1); root xb t0
        fa.featA[0] = xq + 0 * ND; fa.slotA[0] = 0;
        fa.featB[0] = xq + 1 * ND; fa.slotB[0] = 2;
        fa.root[0] = xb + 0 * ND;
        fa.BT[0] = BT + 0 * 768 * DIM; fa.bias[0] = biascat + 0 * DIM;
        fa.Cb[0] = h0; fa.Cq[0] = h0q;
        // z=1 (dst t1): slots 1 (src xq t0), 3 (src xq t2); root xb t1
        fa.featA[1] = xq + 0 * ND; fa.slotA[1] = 1;
        fa.featB[1] = xq + 2 * ND; fa.slotB[1] = 3;
        fa.root[1] = xb + 1 * ND;
        fa.BT[1] = BT + 1 * 768 * DIM; fa.bias[1] = biascat + 1 * DIM;
        fa.Cb[1] = h1; fa.Cq[1] = h1q;
        fa.y = nullptr; fa.nll = nullptr; fa.mode = 0;
        gemm_fused_kernel<<<dim3((NN + 63) / 64, 2), 256, 0, stream>>>(fa, rowstart, esorted);
    }

    // 4. Layer-2 fused gather-GEMM + softmax/nll
    {
        FusedArgs fa;
        fa.featA[0] = h0q; fa.slotA[0] = 0;
        fa.featB[0] = h1q; fa.slotB[0] = 2;
        fa.root[0] = h0;
        fa.BT[0] = BT + 2 * 768 * DIM; fa.bias[0] = biascat + 2 * DIM;
        fa.Cb[0] = nullptr; fa.Cq[0] = nullptr;
        fa.featA[1] = fa.featA[0]; fa.slotA[1] = fa.slotA[0];
        fa.featB[1] = fa.featB[0]; fa.slotB[1] = fa.slotB[0];
        fa.root[1] = fa.root[0]; fa.BT[1] = fa.BT[0]; fa.bias[1] = fa.bias[0];
        fa.Cb[1] = nullptr; fa.Cq[1] = nullptr;
        fa.y = y; fa.nll = nll; fa.mode = 1;
        gemm_fused_kernel<<<dim3((NN + 63) / 64, 1), 256, 0, stream>>>(fa, rowstart, esorted);
    }

    // 5. Mean
    reduce_mean_kernel<<<dim3(1), 256, 0, stream>>>(nll, out);
}

// Round 10
// 304.820 us; speedup vs baseline: 1.2229x; 1.2229x over previous
//
#include <hip/hip_runtime.h>
#include <hip/hip_bf16.h>

#define NN 20000
#define NP1 20001
#define DIM 256
#define NE 320000

#define NBKT 79        // buckets of 256 dst rows (last bucket = 32 rows)
#define BROWS 256
#define ACH 4096       // edges per phase-A chunk
#define ABLK 79        // ceil(NE/ACH)
#define STAGE_CAP 6144

typedef __attribute__((ext_vector_type(8))) short short8v;   // 8 bf16 = 4 VGPRs
typedef __attribute__((ext_vector_type(4))) float float4v;
typedef __attribute__((ext_vector_type(2))) float float2v;
typedef __attribute__((ext_vector_type(8))) unsigned short ushort8v;

typedef __attribute__((address_space(3))) void lds_vp;
typedef const __attribute__((address_space(1))) void gbl_vp;

__device__ __forceinline__ unsigned short f2bf(float f) {
    unsigned int u = __float_as_uint(f);
    u += 0x7fffu + ((u >> 16) & 1u);          // round-to-nearest-even
    return (unsigned short)(u >> 16);
}
__device__ __forceinline__ unsigned char f2fp8(float f) {
    return (unsigned char)(__builtin_amdgcn_cvt_pk_fp8_f32(f, f, 0, 0) & 0xff);
}

__device__ __forceinline__ int slot_to_rel(int s) { return (s == 3) ? 4 : s; }

// ---------------------------------------------------------------------------
// Fused setup: bucket partial hist (atomic-free, private slices) |
// x -> {bf16, fp8} | weight prep
// ---------------------------------------------------------------------------
#define HIST_BLOCKS (4 * ABLK)             // 316
#define CONV_BLOCKS 7500                   // 3*NN*DIM / (256*8)
#define PREP_BLOCKS 768                    // 3 * 256

__global__ __launch_bounds__(256) void setup_kernel(const float* __restrict__ x,
                                                    const int* __restrict__ edges,
                                                    const float* __restrict__ Wr1,
                                                    const float* __restrict__ br1,
                                                    const float* __restrict__ Wo1,
                                                    const float* __restrict__ Wr2,
                                                    const float* __restrict__ br2,
                                                    const float* __restrict__ Wo2,
                                                    int* __restrict__ part,       // [4][ABLK][NBKT]
                                                    unsigned short* __restrict__ xb,
                                                    unsigned char* __restrict__ xq,
                                                    unsigned short* __restrict__ BT,
                                                    float* __restrict__ biascat) {
    int b = blockIdx.x;
    if (b < HIST_BLOCKS) {
        int s = b / ABLK, a = b - s * ABLK;
        int k = slot_to_rel(s);
        __shared__ int cnt[NBKT];
        for (int t = threadIdx.x; t < NBKT; t += 256) cnt[t] = 0;
        __syncthreads();
        int e0 = a * ACH;
        #pragma unroll
        for (int j = 0; j < 16; ++j) {
            int e = e0 + j * 256 + threadIdx.x;
            if (e < NE) atomicAdd(&cnt[edges[k * 2 * NE + NE + e] >> 8], 1);
        }
        __syncthreads();
        for (int t = threadIdx.x; t < NBKT; t += 256)
            part[(s * ABLK + a) * NBKT + t] = cnt[t];
    } else if (b < HIST_BLOCKS + CONV_BLOCKS) {
        size_t i = ((size_t)(b - HIST_BLOCKS) * 256 + threadIdx.x) * 8;
        float4 v0 = *(const float4*)(x + i);
        float4 v1 = *(const float4*)(x + i + 4);
        if (i < 2 * (size_t)NN * DIM) {    // bf16 roots only needed for types 0,1
            ushort8v o;
            o[0] = f2bf(v0.x); o[1] = f2bf(v0.y); o[2] = f2bf(v0.z); o[3] = f2bf(v0.w);
            o[4] = f2bf(v1.x); o[5] = f2bf(v1.y); o[6] = f2bf(v1.z); o[7] = f2bf(v1.w);
            *(ushort8v*)(xb + i) = o;
        }
        unsigned int w0 = __builtin_amdgcn_cvt_pk_fp8_f32(v0.x, v0.y, 0, 0);
        w0 = __builtin_amdgcn_cvt_pk_fp8_f32(v0.z, v0.w, w0, 1);
        unsigned int w1 = __builtin_amdgcn_cvt_pk_fp8_f32(v1.x, v1.y, 0, 0);
        w1 = __builtin_amdgcn_cvt_pk_fp8_f32(v1.z, v1.w, w1, 1);
        *(uint2*)(xq + i) = make_uint2(w0, w1);
    } else {
        int pb = b - HIST_BLOCKS - CONV_BLOCKS;
        int g = pb >> 8, n = pb & 255;
        const float* Wr = (g == 2) ? Wr2 : Wr1;
        const float* Wo = (g == 2) ? Wo2 : Wo1;
        const float* br = (g == 2) ? br2 : br1;
        int ka = (g == 1) ? 1 : 0;
        int kb = (g == 1) ? 4 : 2;
        for (int c = 0; c < 3; ++c) {
            int k = c * 256 + threadIdx.x;
            float v;
            if (k < 256)      v = Wr[(size_t)ka * 65536 + k * 256 + n];
            else if (k < 512) v = Wr[(size_t)kb * 65536 + (k - 256) * 256 + n];
            else              v = Wo[(size_t)ka * 65536 + (k - 512) * 256 + n] +
                                  Wo[(size_t)kb * 65536 + (k - 512) * 256 + n];
            BT[(size_t)g * 768 * 256 + (size_t)n * 768 + k] = f2bf(v);
        }
        if (n == 0) biascat[g * DIM + threadIdx.x] =
            br[ka * DIM + threadIdx.x] + br[kb * DIM + threadIdx.x];
    }
}

// ---------------------------------------------------------------------------
// Phase A: bin edges bucket-major (atomic-free offsets from partial counts)
// ---------------------------------------------------------------------------
__global__ __launch_bounds__(256) void binA_scatter_kernel(const int* __restrict__ edges,
                                                           const int* __restrict__ part,
                                                           uint2* __restrict__ pairs) {
    int s = blockIdx.y, a0 = blockIdx.x;
    int k = slot_to_rel(s);
    const int* P = part + (size_t)s * ABLK * NBKT;
    __shared__ int tot[NBKT], pre[NBKT], bstart[NBKT];
    __shared__ int scn[NBKT], cur[NBKT], gb[NBKT];
    __shared__ uint2 st[ACH];
    if (threadIdx.x < NBKT) {
        int t = threadIdx.x, s_tot = 0, s_pre = 0;
        for (int a = 0; a < ABLK; ++a) {
            int v = P[a * NBKT + t];
            s_tot += v; if (a < a0) s_pre += v;
        }
        tot[t] = s_tot; pre[t] = s_pre;
    }
    __syncthreads();
    if (threadIdx.x == 0) {
        int run = 0;
        for (int b = 0; b < NBKT; ++b) { bstart[b] = run; run += tot[b]; }
        run = 0;
        for (int b = 0; b < NBKT; ++b) { scn[b] = run; run += P[a0 * NBKT + b]; }
    }
    __syncthreads();
    if (threadIdx.x < NBKT) {
        int t = threadIdx.x;
        cur[t] = scn[t];
        gb[t] = bstart[t] + pre[t] - scn[t];
    }
    __syncthreads();
    int e0 = a0 * ACH;
    #pragma unroll
    for (int j = 0; j < 16; ++j) {
        int e = e0 + j * 256 + threadIdx.x;
        if (e < NE) {
            unsigned int src = edges[k * 2 * NE + e];
            unsigned int dst = edges[k * 2 * NE + NE + e];
            int slot = atomicAdd(&cur[dst >> 8], 1);
            st[slot] = make_uint2(src, dst);
        }
    }
    __syncthreads();
    int nthis = NE - e0; if (nthis > ACH) nthis = ACH;
    for (int i = threadIdx.x; i < nthis; i += 256) {
        uint2 p = st[i];
        pairs[(size_t)s * NE + gb[p.y >> 8] + i] = p;
    }
}

// ---------------------------------------------------------------------------
// Phase B: per (bucket, slot) — row counts + scan in LDS -> row_start,
// LDS-atomic scatter to staging, coalesced esorted write.
// ---------------------------------------------------------------------------
__global__ __launch_bounds__(256) void binB_kernel(const uint2* __restrict__ pairs,
                                                   const int* __restrict__ part,
                                                   int* __restrict__ row_start,
                                                   int* __restrict__ esorted) {
    int s = blockIdx.y, b = blockIdx.x;
    const int* P = part + (size_t)s * ABLK * NBKT;
    __shared__ int tot[NBKT], bstartS[NBKT + 1];
    if (threadIdx.x < NBKT) {
        int t = threadIdx.x, s_tot = 0;
        for (int a = 0; a < ABLK; ++a) s_tot += P[a * NBKT + t];
        tot[t] = s_tot;
    }
    __syncthreads();
    if (threadIdx.x == 0) {
        int run = 0;
        for (int j = 0; j < NBKT; ++j) { bstartS[j] = run; run += tot[j]; }
        bstartS[NBKT] = run;
    }
    __syncthreads();
    int base = bstartS[b], end = bstartS[b + 1];
    int n = end - base;
    int row0 = b * BROWS;
    int nrows = NN - row0; if (nrows > BROWS) nrows = BROWS;

    __shared__ int rcnt[BROWS];
    __shared__ int rcur[BROWS];
    __shared__ int stg[STAGE_CAP];
    __shared__ int w4[4];
    rcnt[threadIdx.x] = 0;
    __syncthreads();
    for (int i = threadIdx.x; i < n; i += 256) {
        uint2 p = pairs[(size_t)s * NE + base + i];
        atomicAdd(&rcnt[p.y & 255], 1);
    }
    __syncthreads();
    int lane = threadIdx.x & 63, w = threadIdx.x >> 6;
    int v = rcnt[threadIdx.x];
    int x = v;
    #pragma unroll
    for (int off = 1; off < 64; off <<= 1) {
        int t = __shfl_up(x, off, 64);
        if (lane >= off) x += t;
    }
    if (lane == 63) w4[w] = x;
    __syncthreads();
    int woff = 0;
    for (int j = 0; j < w; ++j) woff += w4[j];
    int excl = x - v + woff;
    if (threadIdx.x < nrows) row_start[s * NP1 + row0 + threadIdx.x] = base + excl;
    if (b == NBKT - 1 && threadIdx.x == 0) row_start[s * NP1 + NN] = end;
    rcur[threadIdx.x] = excl;
    __syncthreads();

    if (n <= STAGE_CAP) {
        for (int i = threadIdx.x; i < n; i += 256) {
            uint2 p = pairs[(size_t)s * NE + base + i];
            int pos = atomicAdd(&rcur[p.y & 255], 1);
            stg[pos] = (int)p.x;
        }
        __syncthreads();
        for (int i = threadIdx.x; i < n; i += 256)
            esorted[(size_t)s * NE + base + i] = stg[i];
    } else {  // pathological fallback
        for (int i = threadIdx.x; i < n; i += 256) {
            uint2 p = pairs[(size_t)s * NE + base + i];
            int pos = atomicAdd(&rcur[p.y & 255], 1);
            esorted[(size_t)s * NE + base + pos] = (int)p.x;
        }
    }
}

// ---------------------------------------------------------------------------
// fp8 aggregation: wave per dst row, quarter-wave per edge, 2-edge unroll.
// Separate kernel (NOT fused into GEMM): R9 showed in-block gather+MFMA
// fusion costs 4-way LDS bank conflicts + kills cross-wave overlap.
// ---------------------------------------------------------------------------
__device__ __forceinline__ void acc_row16(float2v* acc2, uint4 raw) {
    float2v f;
    f = __builtin_amdgcn_cvt_pk_f32_fp8(raw.x, 0); acc2[0] += f;
    f = __builtin_amdgcn_cvt_pk_f32_fp8(raw.x, 1); acc2[1] += f;
    f = __builtin_amdgcn_cvt_pk_f32_fp8(raw.y, 0); acc2[2] += f;
    f = __builtin_amdgcn_cvt_pk_f32_fp8(raw.y, 1); acc2[3] += f;
    f = __builtin_amdgcn_cvt_pk_f32_fp8(raw.z, 0); acc2[4] += f;
    f = __builtin_amdgcn_cvt_pk_f32_fp8(raw.z, 1); acc2[5] += f;
    f = __builtin_amdgcn_cvt_pk_f32_fp8(raw.w, 0); acc2[6] += f;
    f = __builtin_amdgcn_cvt_pk_f32_fp8(raw.w, 1); acc2[7] += f;
}

__device__ __forceinline__ void agg_row_fp8(const unsigned char* feat, int b, int e,
                                            int lane, const int* es,
                                            unsigned short* outrow) {
    int quad = lane >> 4, l = lane & 15;
    float2v acc2[8] = {};
    int i = b + quad;
    for (; i + 4 < e; i += 8) {
        int s0 = es[i];
        int s1 = es[i + 4];
        uint4 r0 = *(const uint4*)(feat + (size_t)s0 * DIM + l * 16);
        uint4 r1 = *(const uint4*)(feat + (size_t)s1 * DIM + l * 16);
        acc_row16(acc2, r0);
        acc_row16(acc2, r1);
    }
    if (i < e) {
        int s0 = es[i];
        uint4 r0 = *(const uint4*)(feat + (size_t)s0 * DIM + l * 16);
        acc_row16(acc2, r0);
    }
    #pragma unroll
    for (int j = 0; j < 8; ++j) {
        acc2[j].x += __shfl_xor(acc2[j].x, 16, 64);
        acc2[j].y += __shfl_xor(acc2[j].y, 16, 64);
        acc2[j].x += __shfl_xor(acc2[j].x, 32, 64);
        acc2[j].y += __shfl_xor(acc2[j].y, 32, 64);
    }
    if (quad == 0) {
        ushort8v o0, o1;
        #pragma unroll
        for (int j = 0; j < 4; ++j) {
            o0[2 * j] = f2bf(acc2[j].x);     o0[2 * j + 1] = f2bf(acc2[j].y);
            o1[2 * j] = f2bf(acc2[4 + j].x); o1[2 * j + 1] = f2bf(acc2[4 + j].y);
        }
        *(ushort8v*)(outrow + l * 16) = o0;
        *(ushort8v*)(outrow + l * 16 + 8) = o1;
    }
}

__global__ __launch_bounds__(256) void aggregate_l1_kernel(const unsigned char* __restrict__ xq,
                                                           const int* __restrict__ row_start,
                                                           const int* __restrict__ esorted,
                                                           unsigned short* __restrict__ aggbase) {
    int s = blockIdx.y;                            // slot 0..3 = rel {0,1,2,4}
    int srct = (s == 2) ? 1 : ((s == 3) ? 2 : 0);
    const unsigned char* feat = xq + (size_t)srct * NN * DIM;
    const int* rs = row_start + s * NP1;
    const int* es = esorted + s * NE;
    unsigned short* out = aggbase + (size_t)s * NN * DIM;
    int w = threadIdx.x >> 6, lane = threadIdx.x & 63;
    int row = blockIdx.x * 4 + w;
    if (row >= NN) return;
    agg_row_fp8(feat, rs[row], rs[row + 1], lane, es, out + (size_t)row * DIM);
}

__global__ __launch_bounds__(256) void aggregate_l2_kernel(const unsigned char* __restrict__ h0q,
                                                           const unsigned char* __restrict__ h1q,
                                                           const int* __restrict__ row_start,
                                                           const int* __restrict__ esorted,
                                                           unsigned short* __restrict__ aggbase) {
    int q = blockIdx.y;                 // 0: rel k0 (src h0) -> slot0; 1: rel k2 (src h1) -> slot2
    int slot = q ? 2 : 0;
    const unsigned char* feat = q ? h1q : h0q;
    const int* rs = row_start + slot * NP1;
    const int* es = esorted + slot * NE;
    unsigned short* out = aggbase + (size_t)slot * NN * DIM;
    int w = threadIdx.x >> 6, lane = threadIdx.x & 63;
    int row = blockIdx.x * 4 + w;
    if (row >= NN) return;
    agg_row_fp8(feat, rs[row], rs[row + 1], lane, es, out + (size_t)row * DIM);
}

// ---------------------------------------------------------------------------
// MFMA bf16 GEMM (layer 1): 128x128 tile, BK=64 via twin BK=32 LDS tiles.
// ---------------------------------------------------------------------------
struct GemmArgs {
    const unsigned short* A0[2];
    const unsigned short* A1[2];
    const unsigned short* A2[2];
    const unsigned short* BT[2];
    const float* bias[2];
    unsigned short* Cb[2];   // bf16 out
    unsigned char* Cq[2];    // fp8 shadow out
    int relu;
    int M;
};

__global__ __launch_bounds__(256) void gemm_mfma_lds_kernel(GemmArgs ga) {
    __shared__ unsigned short Atile[2][128 * 32];
    __shared__ unsigned short Btile[2][128 * 32];
    int z = blockIdx.z;
    const unsigned short* Asrc[3] = {ga.A0[z], ga.A1[z], ga.A2[z]};
    const unsigned short* BT = ga.BT[z];
    int M = ga.M;

    int tid = threadIdx.x;
    int wave = tid >> 6, lane = tid & 63;
    int wr = wave >> 1, wc = wave & 1;
    int row0 = blockIdx.x * 128;
    int col0 = blockIdx.y * 128;
    int q = lane >> 4, r = lane & 15;

    int idx0 = tid, idx1 = 256 + tid;
    int arow0 = idx0 >> 2, arow1 = idx1 >> 2;
    int acol0 = (idx0 & 3) * 8, acol1 = (idx1 & 3) * 8;
    int ra0 = row0 + arow0; if (ra0 > M - 1) ra0 = M - 1;
    int ra1 = row0 + arow1; if (ra1 > M - 1) ra1 = M - 1;
    size_t aoff0 = (size_t)ra0 * DIM + acol0;
    size_t aoff1 = (size_t)ra1 * DIM + acol1;
    size_t boff0 = (size_t)(col0 + arow0) * 768 + acol0;
    size_t boff1 = (size_t)(col0 + arow1) * 768 + acol1;
    int ldsbase0 = (tid & ~63) * 8;
    int ldsbase1 = 2048 + (tid & ~63) * 8;

    float4v acc[4][4] = {};
    #pragma unroll 1
    for (int seg = 0; seg < 3; ++seg) {
        const unsigned short* Ap = Asrc[seg];
        #pragma unroll 1
        for (int kt2 = 0; kt2 < 4; ++kt2) {
            int kl = kt2 * 64;
            int kb = seg * 256 + kl;
            #pragma unroll
            for (int p = 0; p < 2; ++p) {
                __builtin_amdgcn_global_load_lds((gbl_vp*)(Ap + aoff0 + kl + p * 32),
                                                 (lds_vp*)&Atile[p][ldsbase0], 16, 0, 0);
                __builtin_amdgcn_global_load_lds((gbl_vp*)(Ap + aoff1 + kl + p * 32),
                                                 (lds_vp*)&Atile[p][ldsbase1], 16, 0, 0);
                __builtin_amdgcn_global_load_lds((gbl_vp*)(BT + boff0 + kb + p * 32),
                                                 (lds_vp*)&Btile[p][ldsbase0], 16, 0, 0);
                __builtin_amdgcn_global_load_lds((gbl_vp*)(BT + boff1 + kb + p * 32),
                                                 (lds_vp*)&Btile[p][ldsbase1], 16, 0, 0);
            }
            __syncthreads();
            #pragma unroll
            for (int p = 0; p < 2; ++p) {
                short8v a[4], b[4];
                #pragma unroll
                for (int i = 0; i < 4; ++i)
                    a[i] = *(const short8v*)&Atile[p][(wr * 64 + i * 16 + r) * 32 + q * 8];
                #pragma unroll
                for (int j = 0; j < 4; ++j)
                    b[j] = *(const short8v*)&Btile[p][(wc * 64 + j * 16 + r) * 32 + q * 8];
                #pragma unroll
                for (int i = 0; i < 4; ++i)
                    #pragma unroll
                    for (int j = 0; j < 4; ++j)
                        acc[i][j] = __builtin_amdgcn_mfma_f32_16x16x32_bf16(a[i], b[j], acc[i][j], 0, 0, 0);
            }
            __syncthreads();
        }
    }

    // Epilogue. C/D layout: col = r, row = q*4 + e
    unsigned short* Cb = ga.Cb[z];
    unsigned char* Cq = ga.Cq[z];
    int rowW0 = row0 + wr * 64;
    int colW0 = col0 + wc * 64;
    float bj[4];
    #pragma unroll
    for (int j = 0; j < 4; ++j) bj[j] = ga.bias[z][colW0 + j * 16 + r];
    #pragma unroll
    for (int i = 0; i < 4; ++i) {
        int rowb = rowW0 + i * 16 + q * 4;
        #pragma unroll
        for (int e = 0; e < 4; ++e) {
            int rowc = rowb + e;
            if (rowc < M) {
                #pragma unroll
                for (int j = 0; j < 4; ++j) {
                    int col = colW0 + j * 16 + r;
                    float v = acc[i][j][e] + bj[j];
                    if (ga.relu) v = fmaxf(v, 0.f);
                    Cb[(size_t)rowc * DIM + col] = f2bf(v);
                    Cq[(size_t)rowc * DIM + col] = f2fp8(v);
                }
            }
        }
    }
}

// ---------------------------------------------------------------------------
// Fused layer-2 GEMM + loss: 512 threads (8 waves), tile 128x256 (full output
// width) -> in-block softmax/nll, no logits round-trip.
// ---------------------------------------------------------------------------
__global__ __launch_bounds__(512) void gemm_loss_kernel(const unsigned short* __restrict__ A0,
                                                        const unsigned short* __restrict__ A1,
                                                        const unsigned short* __restrict__ A2,
                                                        const unsigned short* __restrict__ BT,
                                                        const float* __restrict__ bias,
                                                        const int* __restrict__ y,
                                                        float* __restrict__ nll) {
    __shared__ unsigned short Atile[2][128 * 32];   // 8 KB each
    __shared__ unsigned short Btile[2][256 * 32];   // 16 KB each
    __shared__ float redm[128][4];
    __shared__ float reds[128][4];
    __shared__ float ylog[128];
    __shared__ int ylds[128];
    const unsigned short* Asrc[3] = {A0, A1, A2};

    int tid = threadIdx.x;
    int wave = tid >> 6, lane = tid & 63;
    int wr = wave >> 2, wc = wave & 3;
    int row0 = blockIdx.x * 128;
    int q = lane >> 4, r = lane & 15;

    if (tid < 128) {
        int rowg = row0 + tid;
        ylds[tid] = (rowg < NN) ? y[rowg] : -1;
    }

    int arow = tid >> 2, acol = (tid & 3) * 8;
    int ra = row0 + arow; if (ra > NN - 1) ra = NN - 1;
    size_t aoff = (size_t)ra * DIM + acol;
    size_t boff0 = (size_t)(tid >> 2) * 768 + (tid & 3) * 8;
    size_t boff1 = (size_t)((tid + 512) >> 2) * 768 + (tid & 3) * 8;
    int ldsA = (tid & ~63) * 8;
    int ldsB0 = (tid & ~63) * 8;
    int ldsB1 = 4096 + (tid & ~63) * 8;

    float4v acc[4][4] = {};
    #pragma unroll 1
    for (int seg = 0; seg < 3; ++seg) {
        const unsigned short* Ap = Asrc[seg];
        #pragma unroll 1
        for (int kt2 = 0; kt2 < 4; ++kt2) {
            int kl = kt2 * 64;
            int kb = seg * 256 + kl;
            #pragma unroll
            for (int p = 0; p < 2; ++p) {
                __builtin_amdgcn_global_load_lds((gbl_vp*)(Ap + aoff + kl + p * 32),
                                                 (lds_vp*)&Atile[p][ldsA], 16, 0, 0);
                __builtin_amdgcn_global_load_lds((gbl_vp*)(BT + boff0 + kb + p * 32),
                                                 (lds_vp*)&Btile[p][ldsB0], 16, 0, 0);
                __builtin_amdgcn_global_load_lds((gbl_vp*)(BT + boff1 + kb + p * 32),
                                                 (lds_vp*)&Btile[p][ldsB1], 16, 0, 0);
            }
            __syncthreads();
            #pragma unroll
            for (int p = 0; p < 2; ++p) {
                short8v a[4], b[4];
                #pragma unroll
                for (int i = 0; i < 4; ++i)
                    a[i] = *(const short8v*)&Atile[p][(wr * 64 + i * 16 + r) * 32 + q * 8];
                #pragma unroll
                for (int j = 0; j < 4; ++j)
                    b[j] = *(const short8v*)&Btile[p][(wc * 64 + j * 16 + r) * 32 + q * 8];
                #pragma unroll
                for (int i = 0; i < 4; ++i)
                    #pragma unroll
                    for (int j = 0; j < 4; ++j)
                        acc[i][j] = __builtin_amdgcn_mfma_f32_16x16x32_bf16(a[i], b[j], acc[i][j], 0, 0, 0);
            }
            __syncthreads();
        }
    }

    float bj[4];
    #pragma unroll
    for (int j = 0; j < 4; ++j) bj[j] = bias[wc * 64 + j * 16 + r];
    #pragma unroll
    for (int i = 0; i < 4; ++i) {
        #pragma unroll
        for (int e = 0; e < 4; ++e) {
            int row_local = wr * 64 + i * 16 + q * 4 + e;
            int ycls = ylds[row_local];
            float v[4];
            float m = -3.4e38f;
            #pragma unroll
            for (int j = 0; j < 4; ++j) {
                v[j] = acc[i][j][e] + bj[j];
                m = fmaxf(m, v[j]);
                int col = wc * 64 + j * 16 + r;
                if (col == ycls) ylog[row_local] = v[j];
            }
            #pragma unroll
            for (int off = 1; off < 16; off <<= 1) m = fmaxf(m, __shfl_xor(m, off, 64));
            float s = __expf(v[0] - m) + __expf(v[1] - m) + __expf(v[2] - m) + __expf(v[3] - m);
            #pragma unroll
            for (int off = 1; off < 16; off <<= 1) s += __shfl_xor(s, off, 64);
            if (r == 0) { redm[row_local][wc] = m; reds[row_local][wc] = s; }
        }
    }
    __syncthreads();
    if (tid < 128) {
        int rowg = row0 + tid;
        if (rowg < NN) {
            float m0 = redm[tid][0], m1 = redm[tid][1], m2 = redm[tid][2], m3 = redm[tid][3];
            float mm = fmaxf(fmaxf(m0, m1), fmaxf(m2, m3));
            float ss = reds[tid][0] * __expf(m0 - mm) + reds[tid][1] * __expf(m1 - mm) +
                       reds[tid][2] * __expf(m2 - mm) + reds[tid][3] * __expf(m3 - mm);
            nll[rowg] = mm + __logf(ss) - ylog[tid];
        }
    }
}

__global__ __launch_bounds__(256) void reduce_mean_kernel(const float* __restrict__ nll,
                                                          float* __restrict__ out) {
    float s = 0.f;
    for (int i = threadIdx.x; i < NN; i += 256) s += nll[i];
    #pragma unroll
    for (int off = 32; off; off >>= 1) s += __shfl_xor(s, off, 64);
    __shared__ float ws_[4];
    int w = threadIdx.x >> 6, lane = threadIdx.x & 63;
    if (lane == 0) ws_[w] = s;
    __syncthreads();
    if (threadIdx.x == 0) out[0] = (ws_[0] + ws_[1] + ws_[2] + ws_[3]) / (float)NN;
}

// ---------------------------------------------------------------------------
extern "C" void kernel_launch(void* const* d_in, const int* in_sizes, int n_in,
                              void* d_out, int out_size, void* d_ws, size_t ws_size,
                              hipStream_t stream) {
    const float* x    = (const float*)d_in[0];
    const int*   edges= (const int*)d_in[1];
    const int*   y    = (const int*)d_in[2];
    const float* Wr1  = (const float*)d_in[3];
    const float* br1  = (const float*)d_in[4];
    const float* Wo1  = (const float*)d_in[5];
    const float* Wr2  = (const float*)d_in[6];
    const float* br2  = (const float*)d_in[7];
    const float* Wo2  = (const float*)d_in[8];
    float* out = (float*)d_out;

    char* ws = (char*)d_ws;
    size_t off = 0;
    auto alloc = [&](size_t bytes) {
        char* p = ws + off;
        off += (bytes + 511) & ~size_t(511);
        return p;
    };
    int*   part          = (int*)alloc(4 * (size_t)ABLK * NBKT * sizeof(int));
    uint2* pairs         = (uint2*)alloc(4 * (size_t)NE * sizeof(uint2));
    int*   rowstart      = (int*)alloc(4 * NP1 * sizeof(int));
    int*   esorted       = (int*)alloc(4 * (size_t)NE * sizeof(int));
    unsigned short* BT      = (unsigned short*)alloc(3 * 768 * (size_t)DIM * 2);
    float*          biascat = (float*)         alloc(3 * DIM * sizeof(float));
    unsigned short* xb      = (unsigned short*)alloc(2 * (size_t)NN * DIM * 2);
    unsigned char*  xq      = (unsigned char*) alloc(3 * (size_t)NN * DIM);
    unsigned short* agg     = (unsigned short*)alloc(4 * (size_t)NN * DIM * 2);
    unsigned short* h0      = (unsigned short*)alloc((size_t)NN * DIM * 2);
    unsigned short* h1      = (unsigned short*)alloc((size_t)NN * DIM * 2);
    unsigned char*  h0q     = (unsigned char*) alloc((size_t)NN * DIM);
    unsigned char*  h1q     = (unsigned char*) alloc((size_t)NN * DIM);
    float*          nll     = (float*)         alloc(NN * sizeof(float));
    (void)in_sizes; (void)n_in; (void)out_size; (void)ws_size;

    const size_t ND = (size_t)NN * DIM;

    // 1. Fused setup (bucket partial hist | x->bf16/fp8 | weights)
    setup_kernel<<<dim3(HIST_BLOCKS + CONV_BLOCKS + PREP_BLOCKS), 256, 0, stream>>>(
        x, edges, Wr1, br1, Wo1, Wr2, br2, Wo2, part, xb, xq, BT, biascat);

    // 2. Bucket sort: bin (atomic-free offsets) -> per-bucket scatter
    binA_scatter_kernel<<<dim3(ABLK, 4), 256, 0, stream>>>(edges, part, pairs);
    binB_kernel<<<dim3(NBKT, 4), 256, 0, stream>>>(pairs, part, rowstart, esorted);

    // 3. Layer-1 aggregation (4 relations, one dispatch)
    aggregate_l1_kernel<<<dim3(NN / 4, 4), 256, 0, stream>>>(xq, rowstart, esorted, agg);

    // 4. Layer-1 MFMA GEMMs, both node types fused via blockIdx.z; h bf16 + fp8
    {
        GemmArgs ga;
        ga.A0[0] = agg + 0 * ND; ga.A1[0] = agg + 2 * ND; ga.A2[0] = xb + 0 * ND;
        ga.A0[1] = agg + 1 * ND; ga.A1[1] = agg + 3 * ND; ga.A2[1] = xb + 1 * ND;
        ga.BT[0] = BT + 0 * 768 * DIM; ga.BT[1] = BT + 1 * 768 * DIM;
        ga.bias[0] = biascat + 0 * DIM; ga.bias[1] = biascat + 1 * DIM;
        ga.Cb[0] = h0; ga.Cb[1] = h1;
        ga.Cq[0] = h0q; ga.Cq[1] = h1q;
        ga.relu = 1; ga.M = NN;
        gemm_mfma_lds_kernel<<<dim3((NN + 127) / 128, 2, 2), 256, 0, stream>>>(ga);
    }

    // 5. Layer-2 aggregation (fp8 gather from h0q/h1q)
    aggregate_l2_kernel<<<dim3(NN / 4, 2), 256, 0, stream>>>(h0q, h1q, rowstart, esorted, agg);

    // 6. Fused layer-2 GEMM + softmax/nll (no logits round-trip)
    gemm_loss_kernel<<<dim3((NN + 127) / 128), 512, 0, stream>>>(
        agg + 0 * ND, agg + 2 * ND, h0, BT + 2 * 768 * DIM, biascat + 2 * DIM, y, nll);

    // 7. Mean
    reduce_mean_kernel<<<dim3(1), 256, 0, stream>>>(nll, out);
}

// Round 11
// 303.189 us; speedup vs baseline: 1.2294x; 1.0054x over previous
//
#include <hip/hip_runtime.h>
#include <hip/hip_bf16.h>

#define NN 20000
#define NP1 20001
#define DIM 256
#define NE 320000

#define NBKT 79        // buckets of 256 dst rows (last bucket = 32 rows)
#define BROWS 256
#define ACH 4096       // edges per phase-A chunk
#define ABLK 79        // ceil(NE/ACH)
#define STAGE_CAP 6144

typedef __attribute__((ext_vector_type(8))) short short8v;   // 8 bf16 = 4 VGPRs
typedef __attribute__((ext_vector_type(4))) float float4v;
typedef __attribute__((ext_vector_type(2))) float float2v;
typedef __attribute__((ext_vector_type(8))) unsigned short ushort8v;

typedef __attribute__((address_space(3))) void lds_vp;
typedef const __attribute__((address_space(1))) void gbl_vp;

__device__ __forceinline__ unsigned short f2bf(float f) {
    unsigned int u = __float_as_uint(f);
    u += 0x7fffu + ((u >> 16) & 1u);          // round-to-nearest-even
    return (unsigned short)(u >> 16);
}
__device__ __forceinline__ unsigned char f2fp8(float f) {
    return (unsigned char)(__builtin_amdgcn_cvt_pk_fp8_f32(f, f, 0, 0) & 0xff);
}

__device__ __forceinline__ int slot_to_rel(int s) { return (s == 3) ? 4 : s; }

// ---------------------------------------------------------------------------
// Fused setup: bucket partial hist (atomic-free, private slices) |
// x -> {bf16, fp8} | weight prep
// ---------------------------------------------------------------------------
#define HIST_BLOCKS (4 * ABLK)             // 316
#define CONV_BLOCKS 7500                   // 3*NN*DIM / (256*8)
#define PREP_BLOCKS 768                    // 3 * 256

__global__ __launch_bounds__(256) void setup_kernel(const float* __restrict__ x,
                                                    const int* __restrict__ edges,
                                                    const float* __restrict__ Wr1,
                                                    const float* __restrict__ br1,
                                                    const float* __restrict__ Wo1,
                                                    const float* __restrict__ Wr2,
                                                    const float* __restrict__ br2,
                                                    const float* __restrict__ Wo2,
                                                    int* __restrict__ part,       // [4][ABLK][NBKT]
                                                    unsigned short* __restrict__ xb,
                                                    unsigned char* __restrict__ xq,
                                                    unsigned short* __restrict__ BT,
                                                    float* __restrict__ biascat) {
    int b = blockIdx.x;
    if (b < HIST_BLOCKS) {
        int s = b / ABLK, a = b - s * ABLK;
        int k = slot_to_rel(s);
        __shared__ int cnt[NBKT];
        for (int t = threadIdx.x; t < NBKT; t += 256) cnt[t] = 0;
        __syncthreads();
        int e0 = a * ACH;
        #pragma unroll
        for (int j = 0; j < 16; ++j) {
            int e = e0 + j * 256 + threadIdx.x;
            if (e < NE) atomicAdd(&cnt[edges[k * 2 * NE + NE + e] >> 8], 1);
        }
        __syncthreads();
        for (int t = threadIdx.x; t < NBKT; t += 256)
            part[(s * ABLK + a) * NBKT + t] = cnt[t];
    } else if (b < HIST_BLOCKS + CONV_BLOCKS) {
        size_t i = ((size_t)(b - HIST_BLOCKS) * 256 + threadIdx.x) * 8;
        float4 v0 = *(const float4*)(x + i);
        float4 v1 = *(const float4*)(x + i + 4);
        if (i < 2 * (size_t)NN * DIM) {    // bf16 roots only needed for types 0,1
            ushort8v o;
            o[0] = f2bf(v0.x); o[1] = f2bf(v0.y); o[2] = f2bf(v0.z); o[3] = f2bf(v0.w);
            o[4] = f2bf(v1.x); o[5] = f2bf(v1.y); o[6] = f2bf(v1.z); o[7] = f2bf(v1.w);
            *(ushort8v*)(xb + i) = o;
        }
        unsigned int w0 = __builtin_amdgcn_cvt_pk_fp8_f32(v0.x, v0.y, 0, 0);
        w0 = __builtin_amdgcn_cvt_pk_fp8_f32(v0.z, v0.w, w0, 1);
        unsigned int w1 = __builtin_amdgcn_cvt_pk_fp8_f32(v1.x, v1.y, 0, 0);
        w1 = __builtin_amdgcn_cvt_pk_fp8_f32(v1.z, v1.w, w1, 1);
        *(uint2*)(xq + i) = make_uint2(w0, w1);
    } else {
        int pb = b - HIST_BLOCKS - CONV_BLOCKS;
        int g = pb >> 8, n = pb & 255;
        const float* Wr = (g == 2) ? Wr2 : Wr1;
        const float* Wo = (g == 2) ? Wo2 : Wo1;
        const float* br = (g == 2) ? br2 : br1;
        int ka = (g == 1) ? 1 : 0;
        int kb = (g == 1) ? 4 : 2;
        for (int c = 0; c < 3; ++c) {
            int k = c * 256 + threadIdx.x;
            float v;
            if (k < 256)      v = Wr[(size_t)ka * 65536 + k * 256 + n];
            else if (k < 512) v = Wr[(size_t)kb * 65536 + (k - 256) * 256 + n];
            else              v = Wo[(size_t)ka * 65536 + (k - 512) * 256 + n] +
                                  Wo[(size_t)kb * 65536 + (k - 512) * 256 + n];
            BT[(size_t)g * 768 * 256 + (size_t)n * 768 + k] = f2bf(v);
        }
        if (n == 0) biascat[g * DIM + threadIdx.x] =
            br[ka * DIM + threadIdx.x] + br[kb * DIM + threadIdx.x];
    }
}

// ---------------------------------------------------------------------------
// Phase A: bin edges bucket-major (atomic-free offsets from partial counts)
// ---------------------------------------------------------------------------
__global__ __launch_bounds__(256) void binA_scatter_kernel(const int* __restrict__ edges,
                                                           const int* __restrict__ part,
                                                           uint2* __restrict__ pairs) {
    int s = blockIdx.y, a0 = blockIdx.x;
    int k = slot_to_rel(s);
    const int* P = part + (size_t)s * ABLK * NBKT;
    __shared__ int tot[NBKT], pre[NBKT], bstart[NBKT];
    __shared__ int scn[NBKT], cur[NBKT], gb[NBKT];
    __shared__ uint2 st[ACH];
    if (threadIdx.x < NBKT) {
        int t = threadIdx.x, s_tot = 0, s_pre = 0;
        for (int a = 0; a < ABLK; ++a) {
            int v = P[a * NBKT + t];
            s_tot += v; if (a < a0) s_pre += v;
        }
        tot[t] = s_tot; pre[t] = s_pre;
    }
    __syncthreads();
    if (threadIdx.x == 0) {
        int run = 0;
        for (int b = 0; b < NBKT; ++b) { bstart[b] = run; run += tot[b]; }
        run = 0;
        for (int b = 0; b < NBKT; ++b) { scn[b] = run; run += P[a0 * NBKT + b]; }
    }
    __syncthreads();
    if (threadIdx.x < NBKT) {
        int t = threadIdx.x;
        cur[t] = scn[t];
        gb[t] = bstart[t] + pre[t] - scn[t];
    }
    __syncthreads();
    int e0 = a0 * ACH;
    #pragma unroll
    for (int j = 0; j < 16; ++j) {
        int e = e0 + j * 256 + threadIdx.x;
        if (e < NE) {
            unsigned int src = edges[k * 2 * NE + e];
            unsigned int dst = edges[k * 2 * NE + NE + e];
            int slot = atomicAdd(&cur[dst >> 8], 1);
            st[slot] = make_uint2(src, dst);
        }
    }
    __syncthreads();
    int nthis = NE - e0; if (nthis > ACH) nthis = ACH;
    for (int i = threadIdx.x; i < nthis; i += 256) {
        uint2 p = st[i];
        pairs[(size_t)s * NE + gb[p.y >> 8] + i] = p;
    }
}

// ---------------------------------------------------------------------------
// Phase B: per (bucket, slot) — row counts + scan in LDS -> row_start,
// LDS-atomic scatter to staging, coalesced esorted write.
// ---------------------------------------------------------------------------
__global__ __launch_bounds__(256) void binB_kernel(const uint2* __restrict__ pairs,
                                                   const int* __restrict__ part,
                                                   int* __restrict__ row_start,
                                                   int* __restrict__ esorted) {
    int s = blockIdx.y, b = blockIdx.x;
    const int* P = part + (size_t)s * ABLK * NBKT;
    __shared__ int tot[NBKT], bstartS[NBKT + 1];
    if (threadIdx.x < NBKT) {
        int t = threadIdx.x, s_tot = 0;
        for (int a = 0; a < ABLK; ++a) s_tot += P[a * NBKT + t];
        tot[t] = s_tot;
    }
    __syncthreads();
    if (threadIdx.x == 0) {
        int run = 0;
        for (int j = 0; j < NBKT; ++j) { bstartS[j] = run; run += tot[j]; }
        bstartS[NBKT] = run;
    }
    __syncthreads();
    int base = bstartS[b], end = bstartS[b + 1];
    int n = end - base;
    int row0 = b * BROWS;
    int nrows = NN - row0; if (nrows > BROWS) nrows = BROWS;

    __shared__ int rcnt[BROWS];
    __shared__ int rcur[BROWS];
    __shared__ int stg[STAGE_CAP];
    __shared__ int w4[4];
    rcnt[threadIdx.x] = 0;
    __syncthreads();
    for (int i = threadIdx.x; i < n; i += 256) {
        uint2 p = pairs[(size_t)s * NE + base + i];
        atomicAdd(&rcnt[p.y & 255], 1);
    }
    __syncthreads();
    int lane = threadIdx.x & 63, w = threadIdx.x >> 6;
    int v = rcnt[threadIdx.x];
    int x = v;
    #pragma unroll
    for (int off = 1; off < 64; off <<= 1) {
        int t = __shfl_up(x, off, 64);
        if (lane >= off) x += t;
    }
    if (lane == 63) w4[w] = x;
    __syncthreads();
    int woff = 0;
    for (int j = 0; j < w; ++j) woff += w4[j];
    int excl = x - v + woff;
    if (threadIdx.x < nrows) row_start[s * NP1 + row0 + threadIdx.x] = base + excl;
    if (b == NBKT - 1 && threadIdx.x == 0) row_start[s * NP1 + NN] = end;
    rcur[threadIdx.x] = excl;
    __syncthreads();

    if (n <= STAGE_CAP) {
        for (int i = threadIdx.x; i < n; i += 256) {
            uint2 p = pairs[(size_t)s * NE + base + i];
            int pos = atomicAdd(&rcur[p.y & 255], 1);
            stg[pos] = (int)p.x;
        }
        __syncthreads();
        for (int i = threadIdx.x; i < n; i += 256)
            esorted[(size_t)s * NE + base + i] = stg[i];
    } else {  // pathological fallback
        for (int i = threadIdx.x; i < n; i += 256) {
            uint2 p = pairs[(size_t)s * NE + base + i];
            int pos = atomicAdd(&rcur[p.y & 255], 1);
            esorted[(size_t)s * NE + base + pos] = (int)p.x;
        }
    }
}

// ---------------------------------------------------------------------------
// fp8 aggregation: wave per dst row, quarter-wave per edge, 2-edge unroll.
// XCD swizzle: relation lives in the LOW bits of blockIdx.x. With round-robin
// block%8 -> XCD placement, relation r maps to XCDs {r, r+4} only, so each
// XCD's L2 sees exactly one 5.1 MB src feature array (vs ~15 MB mixture with
// the relation-in-gridDim.y layout). Correctness-independent of the mapping.
// ---------------------------------------------------------------------------
__device__ __forceinline__ void acc_row16(float2v* acc2, uint4 raw) {
    float2v f;
    f = __builtin_amdgcn_cvt_pk_f32_fp8(raw.x, 0); acc2[0] += f;
    f = __builtin_amdgcn_cvt_pk_f32_fp8(raw.x, 1); acc2[1] += f;
    f = __builtin_amdgcn_cvt_pk_f32_fp8(raw.y, 0); acc2[2] += f;
    f = __builtin_amdgcn_cvt_pk_f32_fp8(raw.y, 1); acc2[3] += f;
    f = __builtin_amdgcn_cvt_pk_f32_fp8(raw.z, 0); acc2[4] += f;
    f = __builtin_amdgcn_cvt_pk_f32_fp8(raw.z, 1); acc2[5] += f;
    f = __builtin_amdgcn_cvt_pk_f32_fp8(raw.w, 0); acc2[6] += f;
    f = __builtin_amdgcn_cvt_pk_f32_fp8(raw.w, 1); acc2[7] += f;
}

__device__ __forceinline__ void agg_row_fp8(const unsigned char* feat, int b, int e,
                                            int lane, const int* es,
                                            unsigned short* outrow) {
    int quad = lane >> 4, l = lane & 15;
    float2v acc2[8] = {};
    int i = b + quad;
    for (; i + 4 < e; i += 8) {
        int s0 = es[i];
        int s1 = es[i + 4];
        uint4 r0 = *(const uint4*)(feat + (size_t)s0 * DIM + l * 16);
        uint4 r1 = *(const uint4*)(feat + (size_t)s1 * DIM + l * 16);
        acc_row16(acc2, r0);
        acc_row16(acc2, r1);
    }
    if (i < e) {
        int s0 = es[i];
        uint4 r0 = *(const uint4*)(feat + (size_t)s0 * DIM + l * 16);
        acc_row16(acc2, r0);
    }
    #pragma unroll
    for (int j = 0; j < 8; ++j) {
        acc2[j].x += __shfl_xor(acc2[j].x, 16, 64);
        acc2[j].y += __shfl_xor(acc2[j].y, 16, 64);
        acc2[j].x += __shfl_xor(acc2[j].x, 32, 64);
        acc2[j].y += __shfl_xor(acc2[j].y, 32, 64);
    }
    if (quad == 0) {
        ushort8v o0, o1;
        #pragma unroll
        for (int j = 0; j < 4; ++j) {
            o0[2 * j] = f2bf(acc2[j].x);     o0[2 * j + 1] = f2bf(acc2[j].y);
            o1[2 * j] = f2bf(acc2[4 + j].x); o1[2 * j + 1] = f2bf(acc2[4 + j].y);
        }
        *(ushort8v*)(outrow + l * 16) = o0;
        *(ushort8v*)(outrow + l * 16 + 8) = o1;
    }
}

__global__ __launch_bounds__(256) void aggregate_l1_kernel(const unsigned char* __restrict__ xq,
                                                           const int* __restrict__ row_start,
                                                           const int* __restrict__ esorted,
                                                           unsigned short* __restrict__ aggbase) {
    int bl = blockIdx.x;
    int s = bl & 3;                                // relation in low bits -> XCD pinning
    int rowblk = bl >> 2;
    int srct = (s == 2) ? 1 : ((s == 3) ? 2 : 0);
    const unsigned char* feat = xq + (size_t)srct * NN * DIM;
    const int* rs = row_start + s * NP1;
    const int* es = esorted + s * NE;
    unsigned short* out = aggbase + (size_t)s * NN * DIM;
    int w = threadIdx.x >> 6, lane = threadIdx.x & 63;
    int row = rowblk * 4 + w;
    if (row >= NN) return;
    agg_row_fp8(feat, rs[row], rs[row + 1], lane, es, out + (size_t)row * DIM);
}

__global__ __launch_bounds__(256) void aggregate_l2_kernel(const unsigned char* __restrict__ h0q,
                                                           const unsigned char* __restrict__ h1q,
                                                           const int* __restrict__ row_start,
                                                           const int* __restrict__ esorted,
                                                           unsigned short* __restrict__ aggbase) {
    int bl = blockIdx.x;
    int q = bl & 1;                                // slot in low bit -> XCD pinning
    int rowblk = bl >> 1;
    int slot = q ? 2 : 0;
    const unsigned char* feat = q ? h1q : h0q;
    const int* rs = row_start + slot * NP1;
    const int* es = esorted + slot * NE;
    unsigned short* out = aggbase + (size_t)slot * NN * DIM;
    int w = threadIdx.x >> 6, lane = threadIdx.x & 63;
    int row = rowblk * 4 + w;
    if (row >= NN) return;
    agg_row_fp8(feat, rs[row], rs[row + 1], lane, es, out + (size_t)row * DIM);
}

// ---------------------------------------------------------------------------
// MFMA bf16 GEMM (layer 1): 128x128 tile, BK=64 via twin BK=32 LDS tiles.
// ---------------------------------------------------------------------------
struct GemmArgs {
    const unsigned short* A0[2];
    const unsigned short* A1[2];
    const unsigned short* A2[2];
    const unsigned short* BT[2];
    const float* bias[2];
    unsigned short* Cb[2];   // bf16 out
    unsigned char* Cq[2];    // fp8 shadow out
    int relu;
    int M;
};

__global__ __launch_bounds__(256) void gemm_mfma_lds_kernel(GemmArgs ga) {
    __shared__ unsigned short Atile[2][128 * 32];
    __shared__ unsigned short Btile[2][128 * 32];
    int z = blockIdx.z;
    const unsigned short* Asrc[3] = {ga.A0[z], ga.A1[z], ga.A2[z]};
    const unsigned short* BT = ga.BT[z];
    int M = ga.M;

    int tid = threadIdx.x;
    int wave = tid >> 6, lane = tid & 63;
    int wr = wave >> 1, wc = wave & 1;
    int row0 = blockIdx.x * 128;
    int col0 = blockIdx.y * 128;
    int q = lane >> 4, r = lane & 15;

    int idx0 = tid, idx1 = 256 + tid;
    int arow0 = idx0 >> 2, arow1 = idx1 >> 2;
    int acol0 = (idx0 & 3) * 8, acol1 = (idx1 & 3) * 8;
    int ra0 = row0 + arow0; if (ra0 > M - 1) ra0 = M - 1;
    int ra1 = row0 + arow1; if (ra1 > M - 1) ra1 = M - 1;
    size_t aoff0 = (size_t)ra0 * DIM + acol0;
    size_t aoff1 = (size_t)ra1 * DIM + acol1;
    size_t boff0 = (size_t)(col0 + arow0) * 768 + acol0;
    size_t boff1 = (size_t)(col0 + arow1) * 768 + acol1;
    int ldsbase0 = (tid & ~63) * 8;
    int ldsbase1 = 2048 + (tid & ~63) * 8;

    float4v acc[4][4] = {};
    #pragma unroll 1
    for (int seg = 0; seg < 3; ++seg) {
        const unsigned short* Ap = Asrc[seg];
        #pragma unroll 1
        for (int kt2 = 0; kt2 < 4; ++kt2) {
            int kl = kt2 * 64;
            int kb = seg * 256 + kl;
            #pragma unroll
            for (int p = 0; p < 2; ++p) {
                __builtin_amdgcn_global_load_lds((gbl_vp*)(Ap + aoff0 + kl + p * 32),
                                                 (lds_vp*)&Atile[p][ldsbase0], 16, 0, 0);
                __builtin_amdgcn_global_load_lds((gbl_vp*)(Ap + aoff1 + kl + p * 32),
                                                 (lds_vp*)&Atile[p][ldsbase1], 16, 0, 0);
                __builtin_amdgcn_global_load_lds((gbl_vp*)(BT + boff0 + kb + p * 32),
                                                 (lds_vp*)&Btile[p][ldsbase0], 16, 0, 0);
                __builtin_amdgcn_global_load_lds((gbl_vp*)(BT + boff1 + kb + p * 32),
                                                 (lds_vp*)&Btile[p][ldsbase1], 16, 0, 0);
            }
            __syncthreads();
            #pragma unroll
            for (int p = 0; p < 2; ++p) {
                short8v a[4], b[4];
                #pragma unroll
                for (int i = 0; i < 4; ++i)
                    a[i] = *(const short8v*)&Atile[p][(wr * 64 + i * 16 + r) * 32 + q * 8];
                #pragma unroll
                for (int j = 0; j < 4; ++j)
                    b[j] = *(const short8v*)&Btile[p][(wc * 64 + j * 16 + r) * 32 + q * 8];
                #pragma unroll
                for (int i = 0; i < 4; ++i)
                    #pragma unroll
                    for (int j = 0; j < 4; ++j)
                        acc[i][j] = __builtin_amdgcn_mfma_f32_16x16x32_bf16(a[i], b[j], acc[i][j], 0, 0, 0);
            }
            __syncthreads();
        }
    }

    // Epilogue. C/D layout: col = r, row = q*4 + e
    unsigned short* Cb = ga.Cb[z];
    unsigned char* Cq = ga.Cq[z];
    int rowW0 = row0 + wr * 64;
    int colW0 = col0 + wc * 64;
    float bj[4];
    #pragma unroll
    for (int j = 0; j < 4; ++j) bj[j] = ga.bias[z][colW0 + j * 16 + r];
    #pragma unroll
    for (int i = 0; i < 4; ++i) {
        int rowb = rowW0 + i * 16 + q * 4;
        #pragma unroll
        for (int e = 0; e < 4; ++e) {
            int rowc = rowb + e;
            if (rowc < M) {
                #pragma unroll
                for (int j = 0; j < 4; ++j) {
                    int col = colW0 + j * 16 + r;
                    float v = acc[i][j][e] + bj[j];
                    if (ga.relu) v = fmaxf(v, 0.f);
                    Cb[(size_t)rowc * DIM + col] = f2bf(v);
                    Cq[(size_t)rowc * DIM + col] = f2fp8(v);
                }
            }
        }
    }
}

// ---------------------------------------------------------------------------
// Fused layer-2 GEMM + loss: 512 threads (8 waves), tile 128x256 (full output
// width) -> in-block softmax/nll, no logits round-trip.
// ---------------------------------------------------------------------------
__global__ __launch_bounds__(512) void gemm_loss_kernel(const unsigned short* __restrict__ A0,
                                                        const unsigned short* __restrict__ A1,
                                                        const unsigned short* __restrict__ A2,
                                                        const unsigned short* __restrict__ BT,
                                                        const float* __restrict__ bias,
                                                        const int* __restrict__ y,
                                                        float* __restrict__ nll) {
    __shared__ unsigned short Atile[2][128 * 32];   // 8 KB each
    __shared__ unsigned short Btile[2][256 * 32];   // 16 KB each
    __shared__ float redm[128][4];
    __shared__ float reds[128][4];
    __shared__ float ylog[128];
    __shared__ int ylds[128];
    const unsigned short* Asrc[3] = {A0, A1, A2};

    int tid = threadIdx.x;
    int wave = tid >> 6, lane = tid & 63;
    int wr = wave >> 2, wc = wave & 3;
    int row0 = blockIdx.x * 128;
    int q = lane >> 4, r = lane & 15;

    if (tid < 128) {
        int rowg = row0 + tid;
        ylds[tid] = (rowg < NN) ? y[rowg] : -1;
    }

    int arow = tid >> 2, acol = (tid & 3) * 8;
    int ra = row0 + arow; if (ra > NN - 1) ra = NN - 1;
    size_t aoff = (size_t)ra * DIM + acol;
    size_t boff0 = (size_t)(tid >> 2) * 768 + (tid & 3) * 8;
    size_t boff1 = (size_t)((tid + 512) >> 2) * 768 + (tid & 3) * 8;
    int ldsA = (tid & ~63) * 8;
    int ldsB0 = (tid & ~63) * 8;
    int ldsB1 = 4096 + (tid & ~63) * 8;

    float4v acc[4][4] = {};
    #pragma unroll 1
    for (int seg = 0; seg < 3; ++seg) {
        const unsigned short* Ap = Asrc[seg];
        #pragma unroll 1
        for (int kt2 = 0; kt2 < 4; ++kt2) {
            int kl = kt2 * 64;
            int kb = seg * 256 + kl;
            #pragma unroll
            for (int p = 0; p < 2; ++p) {
                __builtin_amdgcn_global_load_lds((gbl_vp*)(Ap + aoff + kl + p * 32),
                                                 (lds_vp*)&Atile[p][ldsA], 16, 0, 0);
                __builtin_amdgcn_global_load_lds((gbl_vp*)(BT + boff0 + kb + p * 32),
                                                 (lds_vp*)&Btile[p][ldsB0], 16, 0, 0);
                __builtin_amdgcn_global_load_lds((gbl_vp*)(BT + boff1 + kb + p * 32),
                                                 (lds_vp*)&Btile[p][ldsB1], 16, 0, 0);
            }
            __syncthreads();
            #pragma unroll
            for (int p = 0; p < 2; ++p) {
                short8v a[4], b[4];
                #pragma unroll
                for (int i = 0; i < 4; ++i)
                    a[i] = *(const short8v*)&Atile[p][(wr * 64 + i * 16 + r) * 32 + q * 8];
                #pragma unroll
                for (int j = 0; j < 4; ++j)
                    b[j] = *(const short8v*)&Btile[p][(wc * 64 + j * 16 + r) * 32 + q * 8];
                #pragma unroll
                for (int i = 0; i < 4; ++i)
                    #pragma unroll
                    for (int j = 0; j < 4; ++j)
                        acc[i][j] = __builtin_amdgcn_mfma_f32_16x16x32_bf16(a[i], b[j], acc[i][j], 0, 0, 0);
            }
            __syncthreads();
        }
    }

    float bj[4];
    #pragma unroll
    for (int j = 0; j < 4; ++j) bj[j] = bias[wc * 64 + j * 16 + r];
    #pragma unroll
    for (int i = 0; i < 4; ++i) {
        #pragma unroll
        for (int e = 0; e < 4; ++e) {
            int row_local = wr * 64 + i * 16 + q * 4 + e;
            int ycls = ylds[row_local];
            float v[4];
            float m = -3.4e38f;
            #pragma unroll
            for (int j = 0; j < 4; ++j) {
                v[j] = acc[i][j][e] + bj[j];
                m = fmaxf(m, v[j]);
                int col = wc * 64 + j * 16 + r;
                if (col == ycls) ylog[row_local] = v[j];
            }
            #pragma unroll
            for (int off = 1; off < 16; off <<= 1) m = fmaxf(m, __shfl_xor(m, off, 64));
            float s = __expf(v[0] - m) + __expf(v[1] - m) + __expf(v[2] - m) + __expf(v[3] - m);
            #pragma unroll
            for (int off = 1; off < 16; off <<= 1) s += __shfl_xor(s, off, 64);
            if (r == 0) { redm[row_local][wc] = m; reds[row_local][wc] = s; }
        }
    }
    __syncthreads();
    if (tid < 128) {
        int rowg = row0 + tid;
        if (rowg < NN) {
            float m0 = redm[tid][0], m1 = redm[tid][1], m2 = redm[tid][2], m3 = redm[tid][3];
            float mm = fmaxf(fmaxf(m0, m1), fmaxf(m2, m3));
            float ss = reds[tid][0] * __expf(m0 - mm) + reds[tid][1] * __expf(m1 - mm) +
                       reds[tid][2] * __expf(m2 - mm) + reds[tid][3] * __expf(m3 - mm);
            nll[rowg] = mm + __logf(ss) - ylog[tid];
        }
    }
}

__global__ __launch_bounds__(256) void reduce_mean_kernel(const float* __restrict__ nll,
                                                          float* __restrict__ out) {
    float s = 0.f;
    for (int i = threadIdx.x; i < NN; i += 256) s += nll[i];
    #pragma unroll
    for (int off = 32; off; off >>= 1) s += __shfl_xor(s, off, 64);
    __shared__ float ws_[4];
    int w = threadIdx.x >> 6, lane = threadIdx.x & 63;
    if (lane == 0) ws_[w] = s;
    __syncthreads();
    if (threadIdx.x == 0) out[0] = (ws_[0] + ws_[1] + ws_[2] + ws_[3]) / (float)NN;
}

// ---------------------------------------------------------------------------
extern "C" void kernel_launch(void* const* d_in, const int* in_sizes, int n_in,
                              void* d_out, int out_size, void* d_ws, size_t ws_size,
                              hipStream_t stream) {
    const float* x    = (const float*)d_in[0];
    const int*   edges= (const int*)d_in[1];
    const int*   y    = (const int*)d_in[2];
    const float* Wr1  = (const float*)d_in[3];
    const float* br1  = (const float*)d_in[4];
    const float* Wo1  = (const float*)d_in[5];
    const float* Wr2  = (const float*)d_in[6];
    const float* br2  = (const float*)d_in[7];
    const float* Wo2  = (const float*)d_in[8];
    float* out = (float*)d_out;

    char* ws = (char*)d_ws;
    size_t off = 0;
    auto alloc = [&](size_t bytes) {
        char* p = ws + off;
        off += (bytes + 511) & ~size_t(511);
        return p;
    };
    int*   part          = (int*)alloc(4 * (size_t)ABLK * NBKT * sizeof(int));
    uint2* pairs         = (uint2*)alloc(4 * (size_t)NE * sizeof(uint2));
    int*   rowstart      = (int*)alloc(4 * NP1 * sizeof(int));
    int*   esorted       = (int*)alloc(4 * (size_t)NE * sizeof(int));
    unsigned short* BT      = (unsigned short*)alloc(3 * 768 * (size_t)DIM * 2);
    float*          biascat = (float*)         alloc(3 * DIM * sizeof(float));
    unsigned short* xb      = (unsigned short*)alloc(2 * (size_t)NN * DIM * 2);
    unsigned char*  xq      = (unsigned char*) alloc(3 * (size_t)NN * DIM);
    unsigned short* agg     = (unsigned short*)alloc(4 * (size_t)NN * DIM * 2);
    unsigned short* h0      = (unsigned short*)alloc((size_t)NN * DIM * 2);
    unsigned short* h1      = (unsigned short*)alloc((size_t)NN * DIM * 2);
    unsigned char*  h0q     = (unsigned char*) alloc((size_t)NN * DIM);
    unsigned char*  h1q     = (unsigned char*) alloc((size_t)NN * DIM);
    float*          nll     = (float*)         alloc(NN * sizeof(float));
    (void)in_sizes; (void)n_in; (void)out_size; (void)ws_size;

    const size_t ND = (size_t)NN * DIM;

    // 1. Fused setup (bucket partial hist | x->bf16/fp8 | weights)
    setup_kernel<<<dim3(HIST_BLOCKS + CONV_BLOCKS + PREP_BLOCKS), 256, 0, stream>>>(
        x, edges, Wr1, br1, Wo1, Wr2, br2, Wo2, part, xb, xq, BT, biascat);

    // 2. Bucket sort: bin (atomic-free offsets) -> per-bucket scatter
    binA_scatter_kernel<<<dim3(ABLK, 4), 256, 0, stream>>>(edges, part, pairs);
    binB_kernel<<<dim3(NBKT, 4), 256, 0, stream>>>(pairs, part, rowstart, esorted);

    // 3. Layer-1 aggregation, relation-per-XCD swizzled 1D grid
    aggregate_l1_kernel<<<dim3((NN / 4) * 4), 256, 0, stream>>>(xq, rowstart, esorted, agg);

    // 4. Layer-1 MFMA GEMMs, both node types fused via blockIdx.z; h bf16 + fp8
    {
        GemmArgs ga;
        ga.A0[0] = agg + 0 * ND; ga.A1[0] = agg + 2 * ND; ga.A2[0] = xb + 0 * ND;
        ga.A0[1] = agg + 1 * ND; ga.A1[1] = agg + 3 * ND; ga.A2[1] = xb + 1 * ND;
        ga.BT[0] = BT + 0 * 768 * DIM; ga.BT[1] = BT + 1 * 768 * DIM;
        ga.bias[0] = biascat + 0 * DIM; ga.bias[1] = biascat + 1 * DIM;
        ga.Cb[0] = h0; ga.Cb[1] = h1;
        ga.Cq[0] = h0q; ga.Cq[1] = h1q;
        ga.relu = 1; ga.M = NN;
        gemm_mfma_lds_kernel<<<dim3((NN + 127) / 128, 2, 2), 256, 0, stream>>>(ga);
    }

    // 5. Layer-2 aggregation, slot-per-XCD swizzled 1D grid
    aggregate_l2_kernel<<<dim3((NN / 4) * 2), 256, 0, stream>>>(h0q, h1q, rowstart, esorted, agg);

    // 6. Fused layer-2 GEMM + softmax/nll (no logits round-trip)
    gemm_loss_kernel<<<dim3((NN + 127) / 128), 512, 0, stream>>>(
        agg + 0 * ND, agg + 2 * ND, h0, BT + 2 * 768 * DIM, biascat + 2 * DIM, y, nll);

    // 7. Mean
    reduce_mean_kernel<<<dim3(1), 256, 0, stream>>>(nll, out);
}